// Round 13
// baseline (185.709 us; speedup 1.0000x reference)
//
#include <hip/hip_runtime.h>
#include <hip/hip_fp16.h>

#define Nn 100000
#define Ee 1600000
#define HID 128
#define IN_DIM 5
#define N5 (Nn * IN_DIM)

// dst buckets: 1024 nodes, 98 buckets
#define SHD 10
#define BSZD 1024
#define NBD 98
#define DCAP 18432         // per-dst-bucket capacity (mean 16327, sigma 127)
// src groups: 2048 nodes, 49 groups
#define SHS 11
#define BSZS 2048
#define NBS 49
#define SCAP 36864         // per-src-group capacity (mean 32768, sigma 179)

#define PCHUNK 4000
#define PBLK (Ee / PCHUNK)   // 400

#define PCH1 2048
#define SC1 18               // 18*2048 = 36864 = SCAP
#define PCH2 4096
#define SC2 9                // 9*4096 = 36864

#define CPBS 4               // scan partial chunks per bucket

typedef float f32x4 __attribute__((ext_vector_type(4)));
union F2H { float f; __half2 h; };

// ---------- kernel 1a: partition edges by dst ----------
// drec = (d_local << 17) | src
__global__ __launch_bounds__(512) void partD_kernel(const int* __restrict__ src,
                                                    const int* __restrict__ dst,
                                                    unsigned int* __restrict__ drecs,
                                                    int* __restrict__ dcnt) {
    __shared__ unsigned int stage[PCHUNK];
    __shared__ int hist[NBD + 1];
    __shared__ int cur[NBD];
    __shared__ int gbase[NBD];
    int e0 = blockIdx.x * PCHUNK;
    if (threadIdx.x <= NBD) hist[threadIdx.x] = 0;
    __syncthreads();
    for (int e = e0 + threadIdx.x; e < e0 + PCHUNK; e += 512)
        atomicAdd(&hist[(dst[e] >> SHD) + 1], 1);
    __syncthreads();
    if (threadIdx.x == 0)
        for (int b = 1; b <= NBD; ++b) hist[b] += hist[b - 1];
    __syncthreads();
    if (threadIdx.x < NBD) {
        int c0 = hist[threadIdx.x], c1 = hist[threadIdx.x + 1];
        cur[threadIdx.x] = c0;
        gbase[threadIdx.x] = atomicAdd(&dcnt[threadIdx.x], c1 - c0);
    }
    __syncthreads();
    for (int e = e0 + threadIdx.x; e < e0 + PCHUNK; e += 512) {
        int d = dst[e], s = src[e];
        int b = d >> SHD;
        int slot = atomicAdd(&cur[b], 1);
        stage[slot] = ((unsigned int)(d & (BSZD - 1)) << 17) | (unsigned int)s;
    }
    __syncthreads();
    int wave = threadIdx.x >> 6, lane = threadIdx.x & 63;
    for (int b = wave; b < NBD; b += 8) {
        int c0 = hist[b], len = hist[b + 1] - c0;
        unsigned int* o = drecs + (size_t)b * DCAP + gbase[b];
        for (int i = lane; i < len; i += 64) o[i] = stage[c0 + i];
    }
}

// ---------- kernel 1b: partition edges by src group ----------
// srec = (src_local << 17) | d     (src_local < 2^11, d < 2^17)
__global__ __launch_bounds__(512) void partS_kernel(const int* __restrict__ src,
                                                    const int* __restrict__ dst,
                                                    unsigned int* __restrict__ srecs,
                                                    int* __restrict__ scnt) {
    __shared__ unsigned int stage[PCHUNK];
    __shared__ int hist[NBS + 1];
    __shared__ int cur[NBS];
    __shared__ int gbase[NBS];
    int e0 = blockIdx.x * PCHUNK;
    if (threadIdx.x <= NBS) hist[threadIdx.x] = 0;
    __syncthreads();
    for (int e = e0 + threadIdx.x; e < e0 + PCHUNK; e += 512)
        atomicAdd(&hist[(src[e] >> SHS) + 1], 1);
    __syncthreads();
    if (threadIdx.x == 0)
        for (int b = 1; b <= NBS; ++b) hist[b] += hist[b - 1];
    __syncthreads();
    if (threadIdx.x < NBS) {
        int c0 = hist[threadIdx.x], c1 = hist[threadIdx.x + 1];
        cur[threadIdx.x] = c0;
        gbase[threadIdx.x] = atomicAdd(&scnt[threadIdx.x], c1 - c0);
    }
    __syncthreads();
    for (int e = e0 + threadIdx.x; e < e0 + PCHUNK; e += 512) {
        int s = src[e], d = dst[e];
        int b = s >> SHS;
        int slot = atomicAdd(&cur[b], 1);
        stage[slot] = ((unsigned int)(s & (BSZS - 1)) << 17) | (unsigned int)d;
    }
    __syncthreads();
    int wave = threadIdx.x >> 6, lane = threadIdx.x & 63;
    for (int b = wave; b < NBS; b += 8) {
        int c0 = hist[b], len = hist[b + 1] - c0;
        unsigned int* o = srecs + (size_t)b * SCAP + gbase[b];
        for (int i = lane; i < len; i += 64) o[i] = stage[c0 + i];
    }
}

// ---------- kernel 2: in-degree, one block per dst bucket ----------
__global__ __launch_bounds__(1024) void degbin_kernel(const unsigned int* __restrict__ drecs,
                                                      const int* __restrict__ dcnt,
                                                      float* __restrict__ deg) {
    __shared__ int acc[BSZD];
    int b = blockIdx.x;
    int n = dcnt[b];
    acc[threadIdx.x] = 0;
    __syncthreads();
    const unsigned int* R = drecs + (size_t)b * DCAP;
    int i = (int)threadIdx.x;
    for (; i + 3072 < n; i += 4096) {
        unsigned int ra = R[i], rb = R[i + 1024], rc = R[i + 2048], rd = R[i + 3072];
        atomicAdd(&acc[ra >> 17], 1);
        atomicAdd(&acc[rb >> 17], 1);
        atomicAdd(&acc[rc >> 17], 1);
        atomicAdd(&acc[rd >> 17], 1);
    }
    for (; i < n; i += 1024) atomicAdd(&acc[R[i] >> 17], 1);
    __syncthreads();
    int g = (b << SHD) + threadIdx.x;
    if (g < Nn) deg[g] = (float)acc[threadIdx.x];
}

// ---------- kernel 3: dinv = rsqrt(deg+1); xd16 = packed [f32 x3 | f16 x2] * dinv ----------
__global__ void prep_kernel(const float* __restrict__ x, float* __restrict__ deg_dinv,
                            f32x4* __restrict__ xd16) {
    int i = blockIdx.x * blockDim.x + threadIdx.x;
    if (i < Nn) {
        float di = rsqrtf(deg_dinv[i] + 1.0f);
        deg_dinv[i] = di;
        f32x4 o;
        o.x = x[i * IN_DIM + 0] * di;
        o.y = x[i * IN_DIM + 1] * di;
        o.z = x[i * IN_DIM + 2] * di;
        F2H u;
        u.h = __floats2half2_rn(x[i * IN_DIM + 3] * di, x[i * IN_DIM + 4] * di);
        o.w = u.f;
        xd16[i] = o;
    }
}

// ---------- kernel 4: fill1 — src-windowed value expansion, binned by dst ----------
// window (32KB xd16 slice) lives in LDS: value lookup = LDS read, no cache miss.
__global__ __launch_bounds__(512) void fill1_kernel(const unsigned int* __restrict__ srecs,
                                                    const int* __restrict__ scnt,
                                                    const f32x4* __restrict__ xd16,
                                                    int* __restrict__ vcnt1,
                                                    f32x4* __restrict__ v1pay,
                                                    unsigned short* __restrict__ v1du) {
    __shared__ f32x4 win[BSZS];              // 32 KB
    __shared__ f32x4 pstage[PCH1];           // 32 KB
    __shared__ unsigned short dstage[PCH1];  // 4 KB
    __shared__ int hist[NBD + 1];
    __shared__ int cur[NBD];
    __shared__ int gb[NBD];
    int g = blockIdx.x / SC1, c = blockIdx.x % SC1;
    int n = scnt[g];
    int r0 = min(c * PCH1, n), r1 = min(r0 + PCH1, n);
    int base = g << SHS;
    for (int i = threadIdx.x; i < BSZS; i += 512) {
        int idx = base + i;
        win[i] = (idx < Nn) ? xd16[idx] : (f32x4)(0.f);
    }
    if (threadIdx.x <= NBD) hist[threadIdx.x] = 0;
    __syncthreads();
    const unsigned int* R = srecs + (size_t)g * SCAP;
    for (int i = r0 + threadIdx.x; i < r1; i += 512)
        atomicAdd(&hist[((R[i] & 0x1FFFFu) >> SHD) + 1], 1);
    __syncthreads();
    if (threadIdx.x == 0)
        for (int b = 1; b <= NBD; ++b) hist[b] += hist[b - 1];
    __syncthreads();
    if (threadIdx.x < NBD) {
        cur[threadIdx.x] = hist[threadIdx.x];
        gb[threadIdx.x] = atomicAdd(&vcnt1[threadIdx.x],
                                    hist[threadIdx.x + 1] - hist[threadIdx.x]);
    }
    __syncthreads();
    for (int i = r0 + threadIdx.x; i < r1; i += 512) {
        unsigned int r = R[i];
        int d = (int)(r & 0x1FFFFu), sl = (int)(r >> 17);
        int bb = d >> SHD;
        int slot = atomicAdd(&cur[bb], 1);
        pstage[slot] = win[sl];
        dstage[slot] = (unsigned short)(d & (BSZD - 1));
    }
    __syncthreads();
    int wave = threadIdx.x >> 6, lane = threadIdx.x & 63;
    for (int b = wave; b < NBD; b += 8) {
        int c0 = hist[b], len = hist[b + 1] - c0, g0 = gb[b];
        f32x4* po = v1pay + (size_t)b * DCAP + g0;
        unsigned short* duo = v1du + (size_t)b * DCAP + g0;
        for (int i = lane; i < len; i += 64) { po[i] = pstage[c0 + i]; duo[i] = dstage[c0 + i]; }
    }
}

// ---------- kernel 5: scan1 — stream value-records, LDS accumulate ----------
__global__ __launch_bounds__(512) void scan1_kernel(const f32x4* __restrict__ v1pay,
                                                    const unsigned short* __restrict__ v1du,
                                                    const int* __restrict__ vcnt1,
                                                    float* __restrict__ pre1p) {
    __shared__ float acc[BSZD * IN_DIM];     // 20 KB
    int b = blockIdx.x / CPBS, c = blockIdx.x % CPBS;
    int n = vcnt1[b];
    int r0 = (int)((long long)n * c / CPBS), r1 = (int)((long long)n * (c + 1) / CPBS);
    f32x4* accv = (f32x4*)acc;
    for (int i = threadIdx.x; i < BSZD * IN_DIM / 4; i += 512)
        accv[i] = (f32x4)(0.f);
    __syncthreads();
    const f32x4* P = v1pay + (size_t)b * DCAP;
    const unsigned short* D = v1du + (size_t)b * DCAP;
    for (int i = r0 + (int)threadIdx.x; i < r1; i += 512) {
        f32x4 v = P[i];
        int dl = (int)D[i] * IN_DIM;
        F2H u; u.f = v.w; float2 e = __half22float2(u.h);
        atomicAdd(&acc[dl + 0], v.x);
        atomicAdd(&acc[dl + 1], v.y);
        atomicAdd(&acc[dl + 2], v.z);
        atomicAdd(&acc[dl + 3], e.x);
        atomicAdd(&acc[dl + 4], e.y);
    }
    __syncthreads();
    int base = b << SHD;
    int cnt4 = min(BSZD, Nn - base) * IN_DIM / 4;
    f32x4* o = (f32x4*)(pre1p + (size_t)c * N5 + (size_t)base * IN_DIM);
    for (int j = threadIdx.x; j < cnt4; j += 512) o[j] = accv[j];
}

// ---------- kernel 6: fused partial-reduce + layer-1 finish + ReLU + layer-2 proj ----------
__global__ __launch_bounds__(256) void node1_kernel(const float* __restrict__ pre1p,
                             const f32x4* __restrict__ xd16,
                             const float* __restrict__ W1, const float* __restrict__ b1,
                             const float* __restrict__ W2, const float* __restrict__ dinv,
                             float* __restrict__ h2d) {
    __shared__ float w1s[IN_DIM * HID];
    __shared__ float w2s[HID], b1s[HID];
    int tid = threadIdx.x;
    for (int j = tid; j < IN_DIM * HID; j += 256) w1s[j] = W1[j];
    if (tid < HID) { w2s[tid] = W2[tid]; b1s[tid] = b1[tid]; }
    __syncthreads();
    int nnode = blockIdx.x * 256 + tid;
    if (nnode >= Nn) return;
    float a5[IN_DIM] = {0.f, 0.f, 0.f, 0.f, 0.f};
    #pragma unroll
    for (int c = 0; c < CPBS; ++c) {
        const float* p = pre1p + (size_t)c * N5 + (size_t)nnode * IN_DIM;
        #pragma unroll
        for (int k = 0; k < IN_DIM; ++k) a5[k] += p[k];
    }
    f32x4 s = xd16[nnode];
    F2H u; u.f = s.w; float2 se = __half22float2(u.h);
    float di = dinv[nnode];
    a5[0] = (a5[0] + s.x) * di;
    a5[1] = (a5[1] + s.y) * di;
    a5[2] = (a5[2] + s.z) * di;
    a5[3] = (a5[3] + se.x) * di;
    a5[4] = (a5[4] + se.y) * di;
    float accp = 0.f;
    #pragma unroll
    for (int f = 0; f < HID; ++f) {
        float v = b1s[f];
        #pragma unroll
        for (int k = 0; k < IN_DIM; ++k) v += a5[k] * w1s[k * HID + f];
        v = fmaxf(v, 0.f);
        accp += v * w2s[f];
    }
    h2d[nnode] = accp * di;
}

// ---------- kernel 7: fill2 — h2d window in LDS, scalar value records by dst ----------
__global__ __launch_bounds__(512) void fill2_kernel(const unsigned int* __restrict__ srecs,
                                                    const int* __restrict__ scnt,
                                                    const float* __restrict__ h2d,
                                                    int* __restrict__ vcnt2,
                                                    float* __restrict__ v2val,
                                                    unsigned short* __restrict__ v2du) {
    __shared__ float win[BSZS];              // 8 KB
    __shared__ float vstage[PCH2];           // 16 KB
    __shared__ unsigned short dstage[PCH2];  // 8 KB
    __shared__ int hist[NBD + 1];
    __shared__ int cur[NBD];
    __shared__ int gb[NBD];
    int g = blockIdx.x / SC2, c = blockIdx.x % SC2;
    int n = scnt[g];
    int r0 = min(c * PCH2, n), r1 = min(r0 + PCH2, n);
    int base = g << SHS;
    for (int i = threadIdx.x; i < BSZS; i += 512) {
        int idx = base + i;
        win[i] = (idx < Nn) ? h2d[idx] : 0.f;
    }
    if (threadIdx.x <= NBD) hist[threadIdx.x] = 0;
    __syncthreads();
    const unsigned int* R = srecs + (size_t)g * SCAP;
    for (int i = r0 + threadIdx.x; i < r1; i += 512)
        atomicAdd(&hist[((R[i] & 0x1FFFFu) >> SHD) + 1], 1);
    __syncthreads();
    if (threadIdx.x == 0)
        for (int b = 1; b <= NBD; ++b) hist[b] += hist[b - 1];
    __syncthreads();
    if (threadIdx.x < NBD) {
        cur[threadIdx.x] = hist[threadIdx.x];
        gb[threadIdx.x] = atomicAdd(&vcnt2[threadIdx.x],
                                    hist[threadIdx.x + 1] - hist[threadIdx.x]);
    }
    __syncthreads();
    for (int i = r0 + threadIdx.x; i < r1; i += 512) {
        unsigned int r = R[i];
        int d = (int)(r & 0x1FFFFu), sl = (int)(r >> 17);
        int bb = d >> SHD;
        int slot = atomicAdd(&cur[bb], 1);
        vstage[slot] = win[sl];
        dstage[slot] = (unsigned short)(d & (BSZD - 1));
    }
    __syncthreads();
    int wave = threadIdx.x >> 6, lane = threadIdx.x & 63;
    for (int b = wave; b < NBD; b += 8) {
        int c0 = hist[b], len = hist[b + 1] - c0, g0 = gb[b];
        float* vo = v2val + (size_t)b * DCAP + g0;
        unsigned short* duo = v2du + (size_t)b * DCAP + g0;
        for (int i = lane; i < len; i += 64) { vo[i] = vstage[c0 + i]; duo[i] = dstage[c0 + i]; }
    }
}

// ---------- kernel 8: scan2 — stream scalar records, LDS accumulate ----------
__global__ __launch_bounds__(512) void scan2_kernel(const float* __restrict__ v2val,
                                                    const unsigned short* __restrict__ v2du,
                                                    const int* __restrict__ vcnt2,
                                                    float* __restrict__ out2p) {
    __shared__ float acc[BSZD];              // 4 KB
    int b = blockIdx.x / CPBS, c = blockIdx.x % CPBS;
    int n = vcnt2[b];
    int r0 = (int)((long long)n * c / CPBS), r1 = (int)((long long)n * (c + 1) / CPBS);
    for (int i = threadIdx.x; i < BSZD; i += 512) acc[i] = 0.f;
    __syncthreads();
    const float* V = v2val + (size_t)b * DCAP;
    const unsigned short* D = v2du + (size_t)b * DCAP;
    for (int i = r0 + (int)threadIdx.x; i < r1; i += 512)
        atomicAdd(&acc[D[i]], V[i]);
    __syncthreads();
    int base = b << SHD;
    int cnt = min(BSZD, Nn - base);
    float* o = out2p + (size_t)c * Nn + base;
    for (int j = threadIdx.x; j < cnt; j += 512) o[j] = acc[j];
}

// ---------- kernel 9: final reduce + self-loop + b2 ----------
__global__ void final_kernel(const float* __restrict__ out2p, const float* __restrict__ h2d,
                             const float* __restrict__ dinv, const float* __restrict__ b2,
                             float* __restrict__ out) {
    int n = blockIdx.x * blockDim.x + threadIdx.x;
    if (n < Nn) {
        float v = 0.f;
        #pragma unroll
        for (int c = 0; c < CPBS; ++c) v += out2p[(size_t)c * Nn + n];
        out[n] = (v + h2d[n]) * dinv[n] + b2[0];
    }
}

extern "C" void kernel_launch(void* const* d_in, const int* in_sizes, int n_in,
                              void* d_out, int out_size, void* d_ws, size_t ws_size,
                              hipStream_t stream) {
    const float* x  = (const float*)d_in[0];
    const int*   ei = (const int*)d_in[1];     // [2, E]: src row then dst row
    const float* W1 = (const float*)d_in[2];
    const float* b1 = (const float*)d_in[3];
    const float* W2 = (const float*)d_in[4];
    const float* b2 = (const float*)d_in[5];
    const int* src = ei;
    const int* dst = ei + Ee;
    float* out = (float*)d_out;

    float* fw = (float*)d_ws;
    float* dinv  = fw;                              // N floats
    f32x4* xd16  = (f32x4*)(fw + Nn);               // N f32x4 (1.6 MB)
    float* h2d   = fw + Nn + 4 * Nn;                // N
    float* pre1p = h2d + Nn;                        // CPBS*N5 (8 MB); out2p aliases front
    float* out2p = pre1p;                           // CPBS*Nn (alias: pre1p consumed by node1)
    f32x4* v1pay = (f32x4*)(pre1p + (size_t)CPBS * N5);          // NBD*DCAP f32x4 (28.9 MB)
    unsigned int* drecs = (unsigned int*)v1pay;     // alias: drecs consumed by degbin before fill1
    float* v2val = (float*)v1pay;                   // alias: v1pay consumed by scan1 before fill2
    unsigned short* v1du = (unsigned short*)(v1pay + (size_t)NBD * DCAP);  // NBD*DCAP u16 (3.6 MB)
    unsigned short* v2du = v1du;                    // alias: v1du consumed by scan1
    unsigned int* srecs = (unsigned int*)(v1du + (size_t)NBD * DCAP);      // NBS*SCAP u32 (7.2 MB)
    int* cnts = (int*)(srecs + (size_t)NBS * SCAP); // dcnt[98]+scnt[49]+vcnt1[98]+vcnt2[98]
    int* dcnt  = cnts;
    int* scnt  = cnts + NBD;
    int* vcnt1 = scnt + NBS;
    int* vcnt2 = vcnt1 + NBD;

    (void)hipMemsetAsync(cnts, 0, (NBD + NBS + NBD + NBD) * sizeof(int), stream);

    partD_kernel<<<PBLK, 512, 0, stream>>>(src, dst, drecs, dcnt);
    degbin_kernel<<<NBD, 1024, 0, stream>>>(drecs, dcnt, dinv);
    partS_kernel<<<PBLK, 512, 0, stream>>>(src, dst, srecs, scnt);
    prep_kernel<<<(Nn + 255) / 256, 256, 0, stream>>>(x, dinv, xd16);
    fill1_kernel<<<NBS * SC1, 512, 0, stream>>>(srecs, scnt, xd16, vcnt1, v1pay, v1du);
    scan1_kernel<<<NBD * CPBS, 512, 0, stream>>>(v1pay, v1du, vcnt1, pre1p);
    node1_kernel<<<(Nn + 255) / 256, 256, 0, stream>>>(pre1p, xd16, W1, b1, W2, dinv, h2d);
    fill2_kernel<<<NBS * SC2, 512, 0, stream>>>(srecs, scnt, h2d, vcnt2, v2val, v2du);
    scan2_kernel<<<NBD * CPBS, 512, 0, stream>>>(v2val, v2du, vcnt2, out2p);
    final_kernel<<<(Nn + 255) / 256, 256, 0, stream>>>(out2p, h2d, dinv, b2, out);
}

// Round 14
// 117.477 us; speedup vs baseline: 1.5808x; 1.5808x over previous
//
#include <hip/hip_runtime.h>
#include <hip/hip_fp16.h>

#define Nn 100000
#define Ee 1600000
#define HID 128
#define IN_DIM 5
#define N5 (Nn * IN_DIM)

// ---- bucket geometry: 1024 nodes/bucket, 98 buckets ----
#define SH2 10
#define BSZ2 1024
#define NB2 98
#define BCAP 18432        // expect ~16327, sigma ~128

#define PCHUNK 4000       // edges per partition block
#define PBLK (Ee / PCHUNK)   // 400 blocks

#define CPB 6             // chunks/bucket for gather passes -> grid 588

typedef float f32x4 __attribute__((ext_vector_type(4)));
union F2H { float f; __half2 h; };

// Native LDS float add: relaxed, workgroup scope, result discarded -> ds_add_f32
__device__ __forceinline__ void lds_fadd(float* p, float v) {
    __hip_atomic_fetch_add(p, v, __ATOMIC_RELAXED, __HIP_MEMORY_SCOPE_WORKGROUP);
}

// ---------- kernel 1: one-pass radix partition of the edge list ----------
// rec = (d_local << 17) | src   (src < 2^17, d_local < 2^10)
__global__ __launch_bounds__(512) void partition_kernel(const int* __restrict__ src,
                                                        const int* __restrict__ dst,
                                                        unsigned int* __restrict__ recs,
                                                        int* __restrict__ bcnt) {
    __shared__ unsigned int stage[PCHUNK];   // 16 KB
    __shared__ int hist[NB2 + 1];
    __shared__ int cur[NB2];
    __shared__ int gbase[NB2];
    int e0 = blockIdx.x * PCHUNK;
    if (threadIdx.x <= NB2) hist[threadIdx.x] = 0;
    __syncthreads();
    for (int e = e0 + threadIdx.x; e < e0 + PCHUNK; e += 512)
        atomicAdd(&hist[(dst[e] >> SH2) + 1], 1);
    __syncthreads();
    if (threadIdx.x == 0)
        for (int b = 1; b <= NB2; ++b) hist[b] += hist[b - 1];
    __syncthreads();
    if (threadIdx.x < NB2) {
        int c0 = hist[threadIdx.x], c1 = hist[threadIdx.x + 1];
        cur[threadIdx.x] = c0;
        gbase[threadIdx.x] = atomicAdd(&bcnt[threadIdx.x], c1 - c0);
    }
    __syncthreads();
    for (int e = e0 + threadIdx.x; e < e0 + PCHUNK; e += 512) {
        int d = dst[e], s = src[e];
        int b = d >> SH2;
        int slot = atomicAdd(&cur[b], 1);
        stage[slot] = ((unsigned int)(d & (BSZ2 - 1)) << 17) | (unsigned int)s;
    }
    __syncthreads();
    int wave = threadIdx.x >> 6, lane = threadIdx.x & 63;
    for (int b = wave; b < NB2; b += 8) {
        int c0 = hist[b], len = hist[b + 1] - c0;
        unsigned int* o = recs + (size_t)b * BCAP + gbase[b];
        for (int i = lane; i < len; i += 64) o[i] = stage[c0 + i];
    }
}

// ---------- kernel 2: in-degree, one block per bucket ----------
__global__ __launch_bounds__(1024) void degbin_kernel(const unsigned int* __restrict__ recs,
                                                      const int* __restrict__ bcnt,
                                                      float* __restrict__ deg) {
    __shared__ int acc[BSZ2];                // 4 KB
    int b = blockIdx.x;
    int n = bcnt[b];
    acc[threadIdx.x] = 0;
    __syncthreads();
    const unsigned int* R = recs + (size_t)b * BCAP;
    int i = (int)threadIdx.x;
    for (; i + 3072 < n; i += 4096) {
        unsigned int ra = R[i], rb = R[i + 1024], rc = R[i + 2048], rd = R[i + 3072];
        atomicAdd(&acc[ra >> 17], 1);
        atomicAdd(&acc[rb >> 17], 1);
        atomicAdd(&acc[rc >> 17], 1);
        atomicAdd(&acc[rd >> 17], 1);
    }
    for (; i < n; i += 1024) atomicAdd(&acc[R[i] >> 17], 1);
    __syncthreads();
    int g = (b << SH2) + threadIdx.x;
    if (g < Nn) deg[g] = (float)acc[threadIdx.x];
}

// ---------- kernel 3: dinv = rsqrt(deg+1); xd16 = packed [f32 x3 | f16 x2] * dinv ----------
__global__ void prep_kernel(const float* __restrict__ x, float* __restrict__ deg_dinv,
                            f32x4* __restrict__ xd16) {
    int i = blockIdx.x * blockDim.x + threadIdx.x;
    if (i < Nn) {
        float di = rsqrtf(deg_dinv[i] + 1.0f);
        deg_dinv[i] = di;
        f32x4 o;
        o.x = x[i * IN_DIM + 0] * di;
        o.y = x[i * IN_DIM + 1] * di;
        o.z = x[i * IN_DIM + 2] * di;
        F2H u;
        u.h = __floats2half2_rn(x[i * IN_DIM + 3] * di, x[i * IN_DIM + 4] * di);
        o.w = u.f;
        xd16[i] = o;
    }
}

// ---------- kernel 4: layer-1 input aggregation (native ds_add_f32) ----------
__global__ __launch_bounds__(512) void pre1bin_kernel(const unsigned int* __restrict__ recs,
                                                      const int* __restrict__ bcnt,
                                                      const f32x4* __restrict__ xd16,
                                                      float* __restrict__ pre1p) {
    __shared__ float acc[BSZ2 * IN_DIM];     // 20 KB
    int b = blockIdx.x / CPB, c = blockIdx.x % CPB;
    int n = bcnt[b];
    int r0 = (int)((long long)n * c / CPB), r1 = (int)((long long)n * (c + 1) / CPB);
    f32x4* accv = (f32x4*)acc;
    for (int i = threadIdx.x; i < BSZ2 * IN_DIM / 4; i += 512)
        accv[i] = (f32x4)(0.f);
    __syncthreads();
    const unsigned int* R = recs + (size_t)b * BCAP;
    int i = r0 + (int)threadIdx.x;
    for (; i + 512 < r1; i += 1024) {
        unsigned int ra = R[i], rb = R[i + 512];
        f32x4 va = xd16[ra & 0x1FFFFu];
        f32x4 vb = xd16[rb & 0x1FFFFu];
        F2H ua; ua.f = va.w; float2 ea = __half22float2(ua.h);
        F2H ub; ub.f = vb.w; float2 eb = __half22float2(ub.h);
        int da = (int)(ra >> 17) * IN_DIM, db = (int)(rb >> 17) * IN_DIM;
        lds_fadd(&acc[da + 0], va.x);
        lds_fadd(&acc[da + 1], va.y);
        lds_fadd(&acc[da + 2], va.z);
        lds_fadd(&acc[da + 3], ea.x);
        lds_fadd(&acc[da + 4], ea.y);
        lds_fadd(&acc[db + 0], vb.x);
        lds_fadd(&acc[db + 1], vb.y);
        lds_fadd(&acc[db + 2], vb.z);
        lds_fadd(&acc[db + 3], eb.x);
        lds_fadd(&acc[db + 4], eb.y);
    }
    if (i < r1) {
        unsigned int ra = R[i];
        f32x4 va = xd16[ra & 0x1FFFFu];
        F2H ua; ua.f = va.w; float2 ea = __half22float2(ua.h);
        int da = (int)(ra >> 17) * IN_DIM;
        lds_fadd(&acc[da + 0], va.x);
        lds_fadd(&acc[da + 1], va.y);
        lds_fadd(&acc[da + 2], va.z);
        lds_fadd(&acc[da + 3], ea.x);
        lds_fadd(&acc[da + 4], ea.y);
    }
    __syncthreads();
    int base = b << SH2;
    int cnt4 = min(BSZ2, Nn - base) * IN_DIM / 4;
    f32x4* o = (f32x4*)(pre1p + (size_t)c * N5 + (size_t)base * IN_DIM);
    for (int j = threadIdx.x; j < cnt4; j += 512)
        __builtin_nontemporal_store(accv[j], &o[j]);
}

// ---------- kernel 5: fused partial-reduce + layer-1 finish + ReLU + layer-2 proj ----------
__global__ __launch_bounds__(256) void node1_kernel(const float* __restrict__ pre1p,
                             const f32x4* __restrict__ xd16,
                             const float* __restrict__ W1, const float* __restrict__ b1,
                             const float* __restrict__ W2, const float* __restrict__ dinv,
                             float* __restrict__ h2d) {
    __shared__ float w1s[IN_DIM * HID];
    __shared__ float w2s[HID], b1s[HID];
    int tid = threadIdx.x;
    for (int j = tid; j < IN_DIM * HID; j += 256) w1s[j] = W1[j];
    if (tid < HID) { w2s[tid] = W2[tid]; b1s[tid] = b1[tid]; }
    __syncthreads();
    int nnode = blockIdx.x * 256 + tid;
    if (nnode >= Nn) return;
    float a5[IN_DIM] = {0.f, 0.f, 0.f, 0.f, 0.f};
    #pragma unroll
    for (int c = 0; c < CPB; ++c) {
        const float* p = pre1p + (size_t)c * N5 + (size_t)nnode * IN_DIM;
        #pragma unroll
        for (int k = 0; k < IN_DIM; ++k) a5[k] += p[k];
    }
    f32x4 s = xd16[nnode];
    F2H u; u.f = s.w; float2 se = __half22float2(u.h);
    float di = dinv[nnode];
    a5[0] = (a5[0] + s.x) * di;
    a5[1] = (a5[1] + s.y) * di;
    a5[2] = (a5[2] + s.z) * di;
    a5[3] = (a5[3] + se.x) * di;
    a5[4] = (a5[4] + se.y) * di;
    float accp = 0.f;
    #pragma unroll
    for (int f = 0; f < HID; ++f) {
        float v = b1s[f];
        #pragma unroll
        for (int k = 0; k < IN_DIM; ++k) v += a5[k] * w1s[k * HID + f];
        v = fmaxf(v, 0.f);
        accp += v * w2s[f];
    }
    h2d[nnode] = accp * di;
}

// ---------- kernel 6: layer-2 scalar aggregation (native ds_add_f32) ----------
__global__ __launch_bounds__(512) void out2bin_kernel(const unsigned int* __restrict__ recs,
                                                      const int* __restrict__ bcnt,
                                                      const float* __restrict__ h2d,
                                                      float* __restrict__ outp) {
    __shared__ float acc[BSZ2];              // 4 KB
    int b = blockIdx.x / CPB, c = blockIdx.x % CPB;
    int n = bcnt[b];
    int r0 = (int)((long long)n * c / CPB), r1 = (int)((long long)n * (c + 1) / CPB);
    for (int i = threadIdx.x; i < BSZ2; i += 512) acc[i] = 0.f;
    __syncthreads();
    const unsigned int* R = recs + (size_t)b * BCAP;
    int i = r0 + (int)threadIdx.x;
    for (; i + 512 < r1; i += 1024) {
        unsigned int ra = R[i], rb = R[i + 512];
        float ha = h2d[ra & 0x1FFFFu];
        float hb = h2d[rb & 0x1FFFFu];
        lds_fadd(&acc[ra >> 17], ha);
        lds_fadd(&acc[rb >> 17], hb);
    }
    if (i < r1) {
        unsigned int ra = R[i];
        lds_fadd(&acc[ra >> 17], h2d[ra & 0x1FFFFu]);
    }
    __syncthreads();
    int base = b << SH2;
    int cnt = min(BSZ2, Nn - base);
    float* o = outp + (size_t)c * Nn + base;
    for (int j = threadIdx.x; j < cnt; j += 512)
        __builtin_nontemporal_store(acc[j], &o[j]);
}

// ---------- kernel 7: final reduce + self-loop + b2 ----------
__global__ void final_kernel(const float* __restrict__ outp, const float* __restrict__ h2d,
                             const float* __restrict__ dinv, const float* __restrict__ b2,
                             float* __restrict__ out) {
    int n = blockIdx.x * blockDim.x + threadIdx.x;
    if (n < Nn) {
        float v = 0.f;
        #pragma unroll
        for (int c = 0; c < CPB; ++c) v += outp[(size_t)c * Nn + n];
        out[n] = (v + h2d[n]) * dinv[n] + b2[0];
    }
}

extern "C" void kernel_launch(void* const* d_in, const int* in_sizes, int n_in,
                              void* d_out, int out_size, void* d_ws, size_t ws_size,
                              hipStream_t stream) {
    const float* x  = (const float*)d_in[0];
    const int*   ei = (const int*)d_in[1];     // [2, E]: src row then dst row
    const float* W1 = (const float*)d_in[2];
    const float* b1 = (const float*)d_in[3];
    const float* W2 = (const float*)d_in[4];
    const float* b2 = (const float*)d_in[5];
    const int* src = ei;
    const int* dst = ei + Ee;
    float* out = (float*)d_out;

    float* dinv  = (float*)d_ws;                    // N (deg -> dinv in place)
    f32x4* xd16  = (f32x4*)(dinv + Nn);             // N f32x4 (1.6 MB)
    float* h2d   = (float*)(xd16 + Nn);             // N
    float* outp  = h2d + Nn;                        // CPB*N (2.4 MB)
    float* pre1p = outp + (size_t)CPB * Nn;         // CPB*N5 (12 MB)
    unsigned int* recs = (unsigned int*)(pre1p + (size_t)CPB * N5);  // NB2*BCAP (7.2 MB)
    int* bcnt = (int*)(recs + (size_t)NB2 * BCAP);  // NB2 ints
    (void)hipMemsetAsync(bcnt, 0, NB2 * sizeof(int), stream);

    partition_kernel<<<PBLK, 512, 0, stream>>>(src, dst, recs, bcnt);
    degbin_kernel<<<NB2, 1024, 0, stream>>>(recs, bcnt, dinv);
    prep_kernel<<<(Nn + 255) / 256, 256, 0, stream>>>(x, dinv, xd16);
    pre1bin_kernel<<<NB2 * CPB, 512, 0, stream>>>(recs, bcnt, xd16, pre1p);
    node1_kernel<<<(Nn + 255) / 256, 256, 0, stream>>>(pre1p, xd16, W1, b1, W2, dinv, h2d);
    out2bin_kernel<<<NB2 * CPB, 512, 0, stream>>>(recs, bcnt, h2d, outp);
    final_kernel<<<(Nn + 255) / 256, 256, 0, stream>>>(outp, h2d, dinv, b2, out);
}

// Round 15
// 81.967 us; speedup vs baseline: 2.2656x; 1.4332x over previous
//
#include <hip/hip_runtime.h>
#include <hip/hip_fp16.h>

#define Nn 100000
#define Ee 1600000
#define HID 128
#define IN_DIM 5

// dst buckets: 1024 nodes, 98 buckets
#define SH 10
#define BSZ 1024
#define NB 98
#define BCAP 18432        // per-bucket record capacity (mean 16327, sigma 127)

#define PCHUNK 4000
#define PBLK (Ee / PCHUNK)   // 400 blocks

typedef float f32x4 __attribute__((ext_vector_type(4)));
union F2H { float f; __half2 h; };

// ---------- kernel 1: one-pass radix partition of the edge list ----------
// rec = (d_local << 17) | src   (src < 2^17, d_local < 2^10)
__global__ __launch_bounds__(512) void partition_kernel(const int* __restrict__ src,
                                                        const int* __restrict__ dst,
                                                        unsigned int* __restrict__ recs,
                                                        int* __restrict__ bcnt) {
    __shared__ unsigned int stage[PCHUNK];   // 16 KB
    __shared__ int hist[NB + 1];
    __shared__ int cur[NB];
    __shared__ int gbase[NB];
    int e0 = blockIdx.x * PCHUNK;
    if (threadIdx.x <= NB) hist[threadIdx.x] = 0;
    __syncthreads();
    for (int e = e0 + threadIdx.x; e < e0 + PCHUNK; e += 512)
        atomicAdd(&hist[(dst[e] >> SH) + 1], 1);
    __syncthreads();
    if (threadIdx.x == 0)
        for (int b = 1; b <= NB; ++b) hist[b] += hist[b - 1];
    __syncthreads();
    if (threadIdx.x < NB) {
        int c0 = hist[threadIdx.x], c1 = hist[threadIdx.x + 1];
        cur[threadIdx.x] = c0;
        gbase[threadIdx.x] = atomicAdd(&bcnt[threadIdx.x], c1 - c0);
    }
    __syncthreads();
    for (int e = e0 + threadIdx.x; e < e0 + PCHUNK; e += 512) {
        int d = dst[e], s = src[e];
        int b = d >> SH;
        int slot = atomicAdd(&cur[b], 1);
        stage[slot] = ((unsigned int)(d & (BSZ - 1)) << 17) | (unsigned int)s;
    }
    __syncthreads();
    int wave = threadIdx.x >> 6, lane = threadIdx.x & 63;
    for (int b = wave; b < NB; b += 8) {
        int c0 = hist[b], len = hist[b + 1] - c0;
        unsigned int* o = recs + (size_t)b * BCAP + gbase[b];
        for (int i = lane; i < len; i += 64) o[i] = stage[c0 + i];
    }
}

// ---------- kernel 2: per-bucket counting sort ----------
// counts per node -> exclusive scan -> degc/nodeoff -> scatter src into dst-sorted order
__global__ __launch_bounds__(1024) void sortk_kernel(const unsigned int* __restrict__ recs,
                                                     const int* __restrict__ bcnt,
                                                     int* __restrict__ degc,
                                                     unsigned int* __restrict__ nodeoff,
                                                     unsigned int* __restrict__ ssrc) {
    __shared__ int cnt[BSZ];                 // 4 KB
    __shared__ int scanbuf[BSZ];             // 4 KB
    __shared__ int cur[BSZ];                 // 4 KB
    int b = blockIdx.x, tid = threadIdx.x;
    int n = bcnt[b];
    cnt[tid] = 0;
    __syncthreads();
    const unsigned int* R = recs + (size_t)b * BCAP;
    for (int i = tid; i < n; i += 1024)
        atomicAdd(&cnt[R[i] >> 17], 1);
    __syncthreads();
    int v = cnt[tid];
    scanbuf[tid] = v;
    __syncthreads();
    // Hillis-Steele inclusive scan over 1024 entries
    for (int ofs = 1; ofs < BSZ; ofs <<= 1) {
        int t = (tid >= ofs) ? scanbuf[tid - ofs] : 0;
        __syncthreads();
        scanbuf[tid] += t;
        __syncthreads();
    }
    int excl = scanbuf[tid] - v;
    cur[tid] = excl;
    int g = (b << SH) + tid;
    if (g < Nn) { degc[g] = v; nodeoff[g] = (unsigned int)(b * BCAP + excl); }
    __syncthreads();
    unsigned int* O = ssrc + (size_t)b * BCAP;
    for (int i = tid; i < n; i += 1024) {
        unsigned int r = R[i];
        int pos = atomicAdd(&cur[r >> 17], 1);
        O[pos] = r & 0x1FFFFu;
    }
}

// ---------- kernel 3: dinv = rsqrt(deg+1); xd16 = packed [f32 x3 | f16 x2] * dinv ----------
__global__ void prep_kernel(const float* __restrict__ x, const int* __restrict__ degc,
                            float* __restrict__ dinv, f32x4* __restrict__ xd16) {
    int i = blockIdx.x * blockDim.x + threadIdx.x;
    if (i < Nn) {
        float di = rsqrtf((float)degc[i] + 1.0f);
        dinv[i] = di;
        f32x4 o;
        o.x = x[i * IN_DIM + 0] * di;
        o.y = x[i * IN_DIM + 1] * di;
        o.z = x[i * IN_DIM + 2] * di;
        F2H u;
        u.h = __floats2half2_rn(x[i * IN_DIM + 3] * di, x[i * IN_DIM + 4] * di);
        o.w = u.f;
        xd16[i] = o;
    }
}

// ---------- kernel 4: layer-1 segment reduce + finish + ReLU + layer-2 projection ----------
// one thread per node; zero atomics; gathers are L2-resident (xd16 = 1.6 MB)
__global__ __launch_bounds__(256) void gcn1_kernel(const unsigned int* __restrict__ ssrc,
                                                   const unsigned int* __restrict__ nodeoff,
                                                   const int* __restrict__ degc,
                                                   const f32x4* __restrict__ xd16,
                                                   const float* __restrict__ dinv,
                                                   const float* __restrict__ W1,
                                                   const float* __restrict__ b1,
                                                   const float* __restrict__ W2,
                                                   float* __restrict__ h2d) {
    __shared__ float w1s[IN_DIM * HID];
    __shared__ float w2s[HID], b1s[HID];
    int tid = threadIdx.x;
    for (int j = tid; j < IN_DIM * HID; j += 256) w1s[j] = W1[j];
    if (tid < HID) { w2s[tid] = W2[tid]; b1s[tid] = b1[tid]; }
    __syncthreads();
    int nd = blockIdx.x * 256 + tid;
    if (nd >= Nn) return;
    unsigned int off = nodeoff[nd];
    int len = degc[nd];
    float a0 = 0.f, a1 = 0.f, a2 = 0.f, a3 = 0.f, a4 = 0.f;
    int i = 0;
    for (; i + 4 <= len; i += 4) {
        unsigned int s0 = ssrc[off + i], s1 = ssrc[off + i + 1];
        unsigned int s2 = ssrc[off + i + 2], s3 = ssrc[off + i + 3];
        f32x4 v0 = xd16[s0], v1 = xd16[s1], v2 = xd16[s2], v3 = xd16[s3];
        F2H u0, u1, u2, u3;
        u0.f = v0.w; u1.f = v1.w; u2.f = v2.w; u3.f = v3.w;
        float2 e0 = __half22float2(u0.h), e1 = __half22float2(u1.h);
        float2 e2 = __half22float2(u2.h), e3 = __half22float2(u3.h);
        a0 += (v0.x + v1.x) + (v2.x + v3.x);
        a1 += (v0.y + v1.y) + (v2.y + v3.y);
        a2 += (v0.z + v1.z) + (v2.z + v3.z);
        a3 += (e0.x + e1.x) + (e2.x + e3.x);
        a4 += (e0.y + e1.y) + (e2.y + e3.y);
    }
    for (; i < len; ++i) {
        unsigned int s = ssrc[off + i];
        f32x4 v = xd16[s];
        F2H u; u.f = v.w; float2 e = __half22float2(u.h);
        a0 += v.x; a1 += v.y; a2 += v.z; a3 += e.x; a4 += e.y;
    }
    float di = dinv[nd];
    f32x4 sv = xd16[nd];
    F2H su; su.f = sv.w; float2 se = __half22float2(su.h);
    a0 = (a0 + sv.x) * di;
    a1 = (a1 + sv.y) * di;
    a2 = (a2 + sv.z) * di;
    a3 = (a3 + se.x) * di;
    a4 = (a4 + se.y) * di;
    float accp = 0.f;
    #pragma unroll
    for (int f = 0; f < HID; ++f) {
        float v = b1s[f] + a0 * w1s[f] + a1 * w1s[HID + f] + a2 * w1s[2 * HID + f]
                + a3 * w1s[3 * HID + f] + a4 * w1s[4 * HID + f];
        accp += fmaxf(v, 0.f) * w2s[f];
    }
    h2d[nd] = accp * di;
}

// ---------- kernel 5: layer-2 segment reduce + self-loop + b2 ----------
__global__ __launch_bounds__(256) void gcn2_kernel(const unsigned int* __restrict__ ssrc,
                                                   const unsigned int* __restrict__ nodeoff,
                                                   const int* __restrict__ degc,
                                                   const float* __restrict__ h2d,
                                                   const float* __restrict__ dinv,
                                                   const float* __restrict__ b2,
                                                   float* __restrict__ out) {
    int nd = blockIdx.x * 256 + threadIdx.x;
    if (nd >= Nn) return;
    unsigned int off = nodeoff[nd];
    int len = degc[nd];
    float s = 0.f;
    int i = 0;
    for (; i + 8 <= len; i += 8) {
        float t0 = h2d[ssrc[off + i]],     t1 = h2d[ssrc[off + i + 1]];
        float t2 = h2d[ssrc[off + i + 2]], t3 = h2d[ssrc[off + i + 3]];
        float t4 = h2d[ssrc[off + i + 4]], t5 = h2d[ssrc[off + i + 5]];
        float t6 = h2d[ssrc[off + i + 6]], t7 = h2d[ssrc[off + i + 7]];
        s += ((t0 + t1) + (t2 + t3)) + ((t4 + t5) + (t6 + t7));
    }
    for (; i < len; ++i) s += h2d[ssrc[off + i]];
    out[nd] = (s + h2d[nd]) * dinv[nd] + b2[0];
}

extern "C" void kernel_launch(void* const* d_in, const int* in_sizes, int n_in,
                              void* d_out, int out_size, void* d_ws, size_t ws_size,
                              hipStream_t stream) {
    const float* x  = (const float*)d_in[0];
    const int*   ei = (const int*)d_in[1];     // [2, E]: src row then dst row
    const float* W1 = (const float*)d_in[2];
    const float* b1 = (const float*)d_in[3];
    const float* W2 = (const float*)d_in[4];
    const float* b2 = (const float*)d_in[5];
    const int* src = ei;
    const int* dst = ei + Ee;
    float* out = (float*)d_out;

    float* dinv = (float*)d_ws;                      // N floats
    f32x4* xd16 = (f32x4*)(dinv + Nn);               // N f32x4 (1.6 MB)
    float* h2d  = (float*)(xd16 + Nn);               // N
    int* degc   = (int*)(h2d + Nn);                  // N ints
    unsigned int* nodeoff = (unsigned int*)(degc + Nn);          // N u32
    unsigned int* recs = nodeoff + Nn;               // NB*BCAP u32 (7.2 MB)
    unsigned int* ssrc = recs + (size_t)NB * BCAP;   // NB*BCAP u32 (7.2 MB)
    int* bcnt = (int*)(ssrc + (size_t)NB * BCAP);    // NB ints

    (void)hipMemsetAsync(bcnt, 0, NB * sizeof(int), stream);

    partition_kernel<<<PBLK, 512, 0, stream>>>(src, dst, recs, bcnt);
    sortk_kernel<<<NB, 1024, 0, stream>>>(recs, bcnt, degc, nodeoff, ssrc);
    prep_kernel<<<(Nn + 255) / 256, 256, 0, stream>>>(x, degc, dinv, xd16);
    gcn1_kernel<<<(Nn + 255) / 256, 256, 0, stream>>>(ssrc, nodeoff, degc, xd16, dinv,
                                                      W1, b1, W2, h2d);
    gcn2_kernel<<<(Nn + 255) / 256, 256, 0, stream>>>(ssrc, nodeoff, degc, h2d, dinv, b2, out);
}

// Round 16
// 77.774 us; speedup vs baseline: 2.3878x; 1.0539x over previous
//
#include <hip/hip_runtime.h>
#include <hip/hip_fp16.h>

#define Nn 100000
#define Ee 1600000
#define HID 128
#define IN_DIM 5

// dst buckets: 1024 nodes, 98 buckets
#define SH 10
#define BSZ 1024
#define NB 98
#define BCAP 18432        // per-bucket record capacity (mean 16327, sigma 127)

#define PCHUNK 4000
#define PBLK (Ee / PCHUNK)   // 400 blocks

typedef float f32x4 __attribute__((ext_vector_type(4)));
union F2H { float f; __half2 h; };

// ---------- kernel 0: zero the bucket counters (replaces 40us fillBuffer) ----------
__global__ void zero_kernel(int* __restrict__ bcnt) {
    if (threadIdx.x < NB) bcnt[threadIdx.x] = 0;
}

// ---------- kernel 1: one-pass radix partition of the edge list ----------
// rec = (d_local << 17) | src   (src < 2^17, d_local < 2^10)
__global__ __launch_bounds__(512) void partition_kernel(const int* __restrict__ src,
                                                        const int* __restrict__ dst,
                                                        unsigned int* __restrict__ recs,
                                                        int* __restrict__ bcnt) {
    __shared__ unsigned int stage[PCHUNK];   // 16 KB
    __shared__ int hist[NB + 1];
    __shared__ int cur[NB];
    __shared__ int gbase[NB];
    int e0 = blockIdx.x * PCHUNK;
    if (threadIdx.x <= NB) hist[threadIdx.x] = 0;
    __syncthreads();
    for (int e = e0 + threadIdx.x; e < e0 + PCHUNK; e += 512)
        atomicAdd(&hist[(dst[e] >> SH) + 1], 1);
    __syncthreads();
    if (threadIdx.x == 0)
        for (int b = 1; b <= NB; ++b) hist[b] += hist[b - 1];
    __syncthreads();
    if (threadIdx.x < NB) {
        int c0 = hist[threadIdx.x], c1 = hist[threadIdx.x + 1];
        cur[threadIdx.x] = c0;
        gbase[threadIdx.x] = atomicAdd(&bcnt[threadIdx.x], c1 - c0);
    }
    __syncthreads();
    for (int e = e0 + threadIdx.x; e < e0 + PCHUNK; e += 512) {
        int d = dst[e], s = src[e];
        int b = d >> SH;
        int slot = atomicAdd(&cur[b], 1);
        stage[slot] = ((unsigned int)(d & (BSZ - 1)) << 17) | (unsigned int)s;
    }
    __syncthreads();
    int wave = threadIdx.x >> 6, lane = threadIdx.x & 63;
    for (int b = wave; b < NB; b += 8) {
        int c0 = hist[b], len = hist[b + 1] - c0;
        unsigned int* o = recs + (size_t)b * BCAP + gbase[b];
        for (int i = lane; i < len; i += 64) o[i] = stage[c0 + i];
    }
}

// ---------- kernel 2: per-bucket counting sort + fused prep ----------
// counts per node -> scan -> degc/nodeoff -> scatter src; also dinv + xd16 for own nodes
__global__ __launch_bounds__(1024) void sortk_kernel(const unsigned int* __restrict__ recs,
                                                     const int* __restrict__ bcnt,
                                                     const float* __restrict__ x,
                                                     int* __restrict__ degc,
                                                     unsigned int* __restrict__ nodeoff,
                                                     unsigned int* __restrict__ ssrc,
                                                     float* __restrict__ dinv,
                                                     f32x4* __restrict__ xd16) {
    __shared__ int cnt[BSZ];                 // 4 KB
    __shared__ int scanbuf[BSZ];             // 4 KB
    __shared__ int cur[BSZ];                 // 4 KB
    int b = blockIdx.x, tid = threadIdx.x;
    int n = bcnt[b];
    cnt[tid] = 0;
    __syncthreads();
    const unsigned int* R = recs + (size_t)b * BCAP;
    for (int i = tid; i < n; i += 1024)
        atomicAdd(&cnt[R[i] >> 17], 1);
    __syncthreads();
    int v = cnt[tid];
    scanbuf[tid] = v;
    __syncthreads();
    // Hillis-Steele inclusive scan over 1024 entries
    for (int ofs = 1; ofs < BSZ; ofs <<= 1) {
        int t = (tid >= ofs) ? scanbuf[tid - ofs] : 0;
        __syncthreads();
        scanbuf[tid] += t;
        __syncthreads();
    }
    int excl = scanbuf[tid] - v;
    cur[tid] = excl;
    int g = (b << SH) + tid;
    if (g < Nn) {
        degc[g] = v;
        nodeoff[g] = (unsigned int)(b * BCAP + excl);
        // fused prep: dinv + packed scaled features
        float di = rsqrtf((float)v + 1.0f);
        dinv[g] = di;
        f32x4 o;
        o.x = x[g * IN_DIM + 0] * di;
        o.y = x[g * IN_DIM + 1] * di;
        o.z = x[g * IN_DIM + 2] * di;
        F2H u;
        u.h = __floats2half2_rn(x[g * IN_DIM + 3] * di, x[g * IN_DIM + 4] * di);
        o.w = u.f;
        xd16[g] = o;
    }
    __syncthreads();
    unsigned int* O = ssrc + (size_t)b * BCAP;
    for (int i = tid; i < n; i += 1024) {
        unsigned int r = R[i];
        int pos = atomicAdd(&cur[r >> 17], 1);
        O[pos] = r & 0x1FFFFu;
    }
}

// ---------- kernel 3: layer-1 segment reduce + finish + ReLU + layer-2 projection ----------
// one thread per node; zero atomics; gathers are L2-resident (xd16 = 1.6 MB)
__global__ __launch_bounds__(256) void gcn1_kernel(const unsigned int* __restrict__ ssrc,
                                                   const unsigned int* __restrict__ nodeoff,
                                                   const int* __restrict__ degc,
                                                   const f32x4* __restrict__ xd16,
                                                   const float* __restrict__ dinv,
                                                   const float* __restrict__ W1,
                                                   const float* __restrict__ b1,
                                                   const float* __restrict__ W2,
                                                   float* __restrict__ h2d) {
    __shared__ float w1s[IN_DIM * HID];
    __shared__ float w2s[HID], b1s[HID];
    int tid = threadIdx.x;
    for (int j = tid; j < IN_DIM * HID; j += 256) w1s[j] = W1[j];
    if (tid < HID) { w2s[tid] = W2[tid]; b1s[tid] = b1[tid]; }
    __syncthreads();
    int nd = blockIdx.x * 256 + tid;
    if (nd >= Nn) return;
    unsigned int off = nodeoff[nd];
    int len = degc[nd];
    float a0 = 0.f, a1 = 0.f, a2 = 0.f, a3 = 0.f, a4 = 0.f;
    int i = 0;
    for (; i + 4 <= len; i += 4) {
        unsigned int s0 = ssrc[off + i], s1 = ssrc[off + i + 1];
        unsigned int s2 = ssrc[off + i + 2], s3 = ssrc[off + i + 3];
        f32x4 v0 = xd16[s0], v1 = xd16[s1], v2 = xd16[s2], v3 = xd16[s3];
        F2H u0, u1, u2, u3;
        u0.f = v0.w; u1.f = v1.w; u2.f = v2.w; u3.f = v3.w;
        float2 e0 = __half22float2(u0.h), e1 = __half22float2(u1.h);
        float2 e2 = __half22float2(u2.h), e3 = __half22float2(u3.h);
        a0 += (v0.x + v1.x) + (v2.x + v3.x);
        a1 += (v0.y + v1.y) + (v2.y + v3.y);
        a2 += (v0.z + v1.z) + (v2.z + v3.z);
        a3 += (e0.x + e1.x) + (e2.x + e3.x);
        a4 += (e0.y + e1.y) + (e2.y + e3.y);
    }
    for (; i < len; ++i) {
        unsigned int s = ssrc[off + i];
        f32x4 v = xd16[s];
        F2H u; u.f = v.w; float2 e = __half22float2(u.h);
        a0 += v.x; a1 += v.y; a2 += v.z; a3 += e.x; a4 += e.y;
    }
    float di = dinv[nd];
    f32x4 sv = xd16[nd];
    F2H su; su.f = sv.w; float2 se = __half22float2(su.h);
    a0 = (a0 + sv.x) * di;
    a1 = (a1 + sv.y) * di;
    a2 = (a2 + sv.z) * di;
    a3 = (a3 + se.x) * di;
    a4 = (a4 + se.y) * di;
    float accp = 0.f;
    #pragma unroll
    for (int f = 0; f < HID; ++f) {
        float v = b1s[f] + a0 * w1s[f] + a1 * w1s[HID + f] + a2 * w1s[2 * HID + f]
                + a3 * w1s[3 * HID + f] + a4 * w1s[4 * HID + f];
        accp += fmaxf(v, 0.f) * w2s[f];
    }
    h2d[nd] = accp * di;
}

// ---------- kernel 4: layer-2 segment reduce + self-loop + b2 ----------
__global__ __launch_bounds__(256) void gcn2_kernel(const unsigned int* __restrict__ ssrc,
                                                   const unsigned int* __restrict__ nodeoff,
                                                   const int* __restrict__ degc,
                                                   const float* __restrict__ h2d,
                                                   const float* __restrict__ dinv,
                                                   const float* __restrict__ b2,
                                                   float* __restrict__ out) {
    int nd = blockIdx.x * 256 + threadIdx.x;
    if (nd >= Nn) return;
    unsigned int off = nodeoff[nd];
    int len = degc[nd];
    float s = 0.f;
    int i = 0;
    for (; i + 8 <= len; i += 8) {
        float t0 = h2d[ssrc[off + i]],     t1 = h2d[ssrc[off + i + 1]];
        float t2 = h2d[ssrc[off + i + 2]], t3 = h2d[ssrc[off + i + 3]];
        float t4 = h2d[ssrc[off + i + 4]], t5 = h2d[ssrc[off + i + 5]];
        float t6 = h2d[ssrc[off + i + 6]], t7 = h2d[ssrc[off + i + 7]];
        s += ((t0 + t1) + (t2 + t3)) + ((t4 + t5) + (t6 + t7));
    }
    for (; i < len; ++i) s += h2d[ssrc[off + i]];
    out[nd] = (s + h2d[nd]) * dinv[nd] + b2[0];
}

extern "C" void kernel_launch(void* const* d_in, const int* in_sizes, int n_in,
                              void* d_out, int out_size, void* d_ws, size_t ws_size,
                              hipStream_t stream) {
    const float* x  = (const float*)d_in[0];
    const int*   ei = (const int*)d_in[1];     // [2, E]: src row then dst row
    const float* W1 = (const float*)d_in[2];
    const float* b1 = (const float*)d_in[3];
    const float* W2 = (const float*)d_in[4];
    const float* b2 = (const float*)d_in[5];
    const int* src = ei;
    const int* dst = ei + Ee;
    float* out = (float*)d_out;

    float* dinv = (float*)d_ws;                      // N floats
    f32x4* xd16 = (f32x4*)(dinv + Nn);               // N f32x4 (1.6 MB)
    float* h2d  = (float*)(xd16 + Nn);               // N
    int* degc   = (int*)(h2d + Nn);                  // N ints
    unsigned int* nodeoff = (unsigned int*)(degc + Nn);          // N u32
    unsigned int* recs = nodeoff + Nn;               // NB*BCAP u32 (7.2 MB)
    unsigned int* ssrc = recs + (size_t)NB * BCAP;   // NB*BCAP u32 (7.2 MB)
    int* bcnt = (int*)(ssrc + (size_t)NB * BCAP);    // NB ints

    zero_kernel<<<1, 128, 0, stream>>>(bcnt);
    partition_kernel<<<PBLK, 512, 0, stream>>>(src, dst, recs, bcnt);
    sortk_kernel<<<NB, 1024, 0, stream>>>(recs, bcnt, x, degc, nodeoff, ssrc, dinv, xd16);
    gcn1_kernel<<<(Nn + 255) / 256, 256, 0, stream>>>(ssrc, nodeoff, degc, xd16, dinv,
                                                      W1, b1, W2, h2d);
    gcn2_kernel<<<(Nn + 255) / 256, 256, 0, stream>>>(ssrc, nodeoff, degc, h2d, dinv, b2, out);
}